// Round 4
// baseline (140.968 us; speedup 1.0000x reference)
//
#include <hip/hip_runtime.h>
#include <hip/hip_bf16.h>

typedef __attribute__((ext_vector_type(8))) short short8;
typedef __attribute__((ext_vector_type(4))) short short4v;
typedef __attribute__((ext_vector_type(4))) float floatx4;

#define SEQ   2048
#define EMB   1024
#define HEAD  64
#define BATCH 8

// bf16 via round-half-up (2 VALU ops; ties P=2^-16, stats == RNE)
__device__ __forceinline__ short f2bf(float f) {
    union { float f; unsigned u; } a; a.f = f;
    return (short)((a.u + 0x8000u) >> 16);
}

__device__ __forceinline__ short8 pk8(floatx4 a, floatx4 b) {
    short8 r;
    #pragma unroll
    for (int i = 0; i < 4; ++i) {
        union { float f; unsigned u; } x1, x2;
        x1.f = a[i]; x2.f = b[i];
        r[i]     = (short)((x1.u + 0x8000u) >> 16);
        r[4 + i] = (short)((x2.u + 0x8000u) >> 16);
    }
    return r;
}

// async global->LDS, 16B per lane; LDS dst = uniform base + lane*16
__device__ __forceinline__ void gld16(const void* g, void* l) {
    __builtin_amdgcn_global_load_lds(
        (const __attribute__((address_space(1))) unsigned int*)g,
        (__attribute__((address_space(3))) unsigned int*)l,
        16, 0, 0);
}

// Wf: MFMA-fragment-ordered weights, bf16.
// fragid f = (mat*4 + nt)*32 + kchunk, mat 0=Wq 1=Wk 2=Wv.
// Wf[f*512 + lane*8 + j] = W[k = kchunk*32 + (lane>>4)*8 + j][h = nt*16 + (lane&15)]
__global__ void wtrans_kernel(const float* __restrict__ Wk,
                              const float* __restrict__ Wq,
                              const float* __restrict__ Wv,
                              short* __restrict__ Wf) {
    int gid  = blockIdx.x * 256 + threadIdx.x;   // 24576 total
    int lane = gid & 63;
    int fid  = gid >> 6;
    int chunk = fid & 31;
    int mnt  = fid >> 5;
    int mat  = mnt >> 2, nt = mnt & 3;
    const float* src = (mat == 0) ? Wq : (mat == 1) ? Wk : Wv;
    int n = lane & 15, quad = lane >> 4;
    int h = nt * 16 + n;
    short8 o8;
    #pragma unroll
    for (int j = 0; j < 8; ++j)
        o8[j] = f2bf(src[(chunk * 32 + quad * 8 + j) * 64 + h]);
    *(short8*)(Wf + (long)gid * 8) = o8;
}

// QKV v4: block = 64 rows, 512 threads, 8 waves = (rg = 16-row group, 0..3)
// x (nh = 96-col half) -> 2 waves/SIMD (was 1): one wave's MFMA phase hides
// the other's pk8/ds_read/x-load latency, same mechanism as the attn R1 win.
// Pure M-split: each wave owns 6 acc frags, no merge needed. LW layout,
// double-buffer and barrier structure identical to R3; x register
// double-buffer kept (paired even/odd loop, static xva/xvb alternation).
__global__ __launch_bounds__(512, 1) void qkv_kernel(const float* __restrict__ x,
                                                     const short* __restrict__ Wf,
                                                     short* __restrict__ q,
                                                     short* __restrict__ k,
                                                     short* __restrict__ vt) {
    __shared__ short LW[2][12][4][64][8];   // 96 KB: [buf][mnt][kchunk][lane][8]
    const int wv   = threadIdx.x >> 6;      // 0..7
    const int lane = threadIdx.x & 63;
    const int l15  = lane & 15;
    const int quad = lane >> 4;
    const int rg   = wv >> 1;              // row group (16 rows), 0..3
    const int nh   = wv & 1;               // N half (6 ntiles)
    const int row0 = blockIdx.x * 64;

    floatx4 acc[6];
    #pragma unroll
    for (int f = 0; f < 6; ++f) acc[f] = (floatx4){0.f, 0.f, 0.f, 0.f};

    const float* xr0 = x + (long)(row0 + rg * 16 + l15) * EMB + quad * 8;

    floatx4 xva[8], xvb[8];

    auto stageW = [&](int gnext, int dst) {
        #pragma unroll
        for (int i = 0; i < 6; ++i) {
            const int s = wv * 6 + i, mnt = s >> 2, c = s & 3;
            gld16(Wf + (long)(mnt * 32 + gnext * 4 + c) * 512 + lane * 8,
                  &LW[dst][mnt][c][0][0]);
        }
    };
    auto loadx = [&](floatx4 (&xv)[8], int g) {
        #pragma unroll
        for (int c = 0; c < 4; ++c) {
            const float* p0 = xr0 + g * 128 + c * 32;
            xv[2 * c + 0] = *(const floatx4*)(p0);
            xv[2 * c + 1] = *(const floatx4*)(p0 + 4);
        }
    };
    auto compute = [&](int bb, floatx4 (&xc)[8]) {
        #pragma unroll
        for (int c = 0; c < 4; ++c) {
            short8 a0 = pk8(xc[2 * c + 0], xc[2 * c + 1]);
            #pragma unroll
            for (int i = 0; i < 6; ++i) {
                short8 bf = *(const short8*)&LW[bb][nh * 6 + i][c][lane][0];
                acc[i] = __builtin_amdgcn_mfma_f32_16x16x32_bf16(a0, bf, acc[i], 0, 0, 0);
            }
        }
    };

    stageW(0, 0);
    loadx(xva, 0);
    __syncthreads();

    #pragma unroll 1
    for (int t = 0; t < 4; ++t) {
        const int g0 = 2 * t;
        // even group g0: consume xva + LW[0]; prefetch g0+1 -> LW[1], xvb
        stageW(g0 + 1, 1);
        loadx(xvb, g0 + 1);
        compute(0, xva);
        __syncthreads();
        // odd group g0+1: consume xvb + LW[1]; prefetch g0+2 -> LW[0], xva
        if (t < 3) {
            stageW(g0 + 2, 0);
            loadx(xva, g0 + 2);
        }
        compute(1, xvb);
        __syncthreads();
    }

    // epilogue: wave owns rows rg*16..+15, ntiles nh*6..+5
    const int bidx = row0 >> 11;
    #pragma unroll
    for (int i = 0; i < 6; ++i) {
        const int mnt = nh * 6 + i;
        const int mat = mnt >> 2, ntl = mnt & 3;
        const int col = ntl * 16 + l15;
        const floatx4 av = acc[i];
        const long rbase = row0 + rg * 16 + quad * 4;
        if (mat == 0) {
            #pragma unroll
            for (int r = 0; r < 4; ++r)
                q[(rbase + r) * HEAD + col] = f2bf(av[r]);
        } else if (mat == 1) {
            #pragma unroll
            for (int r = 0; r < 4; ++r)
                k[(rbase + r) * HEAD + col] = f2bf(av[r]);
        } else {
            short4v vv;
            #pragma unroll
            for (int r = 0; r < 4; ++r) vv[r] = f2bf(av[r]);
            const int srow = (int)(rbase & (SEQ - 1));
            *(short4v*)(vt + ((long)bidx * HEAD + col) * SEQ + srow) = vv;
        }
    }
}

// Attention v2 (unchanged from the round-1/round-3 version): block = tile pair
// (p, 63-p) of 32 q-rows each -> ~33 BK=64 chunks, uniform across all 256
// blocks. 8 waves = (par = chunk parity) x (kh = key-half) x (rg = row-group):
// par=0 waves process even chunks, par=1 odd chunks -> 2 waves/SIMD,
// one barrier per TWO chunks. Fixed-base softmax exp(s/8-16) => all
// (kh,par) partials merge by plain sum in the epilogue.
__global__ __launch_bounds__(512, 2) void attn_kernel(const short* __restrict__ q,
                                                      const short* __restrict__ k,
                                                      const short* __restrict__ vt,
                                                      float* __restrict__ out) {
    // LDS arena: main loop KV 64 KB + Plds 10 KB; epilogue overlays oM 48 KB
    // + lM 768 B on the same region (KV dead after final loop barrier).
    __shared__ __align__(16) char smem[75776];
    auto KV   = (short (*)[2][16][64][8])smem;        // [bb][par][fid][lane][j]
    auto Plds = (short (*)[16][40])(smem + 65536);    // [wv][row][col]
    float* oM = (float*)smem;                         // [tile2][slot3][rg2][row16][col64]
    float* lM = (float*)(smem + 49152);               // [tile2][slot3][rg2][row16]

    const int wv   = (int)threadIdx.x >> 6;
    const int lane = (int)threadIdx.x & 63;
    const int l15  = lane & 15;
    const int quad = lane >> 4;
    const int ws   = wv & 3;               // sub-id within parity group
    const int rg   = ws & 1;               // row-group within 32-row tile
    const int kh   = ws >> 1;              // key-half within BK=64 chunk
    const int par  = wv >> 2;              // chunk parity
    const int b    = blockIdx.x & 7;
    const int p    = blockIdx.x >> 3;      // 0..31
    const int t2   = 63 - p;
    const int s1   = p * 32, s2 = t2 * 32;
    const int nch1 = (p >> 1) + 1;         // 1..16
    const int nch2 = (t2 >> 1) + 1;        // 17..32; nch1+nch2 == 33

    const short* kbase = k  + (long)b * SEQ * HEAD;
    const short* vbase = vt + (long)b * HEAD * SEQ;

    const short* q1p = q + ((long)b * SEQ + s1 + rg * 16 + l15) * HEAD + quad * 8;
    const short* q2p = q + ((long)b * SEQ + s2 + rg * 16 + l15) * HEAD + quad * 8;
    short8 q1f0 = *(const short8*)(q1p), q1f1 = *(const short8*)(q1p + 32);
    short8 q2f0 = *(const short8*)(q2p), q2f1 = *(const short8*)(q2p + 32);

    floatx4 o1[4], o2[4];
    #pragma unroll
    for (int nhh = 0; nhh < 4; ++nhh) {
        o1[nhh] = (floatx4){0.f, 0.f, 0.f, 0.f};
        o2[nhh] = (floatx4){0.f, 0.f, 0.f, 0.f};
    }
    float l1[4] = {0.f, 0.f, 0.f, 0.f};
    float l2[4] = {0.f, 0.f, 0.f, 0.f};

    // stage one chunk of this wave's parity into KV[bb][par]; 4 waves/parity
    // cover 16 frags (fid 0-7 K, 8-15 V) at 4 gld16 per wave.
    auto stage = [&](int ch, int bb) {
        const int j0 = ch * 64;
        #pragma unroll
        for (int i = 0; i < 2; ++i) {
            const int fid = ws + i * 4;            // K frag: (ntg<<1)|ks
            const int ntg = fid >> 1, ks = fid & 1;
            gld16(kbase + (long)(j0 + ntg * 16 + l15) * HEAD + ks * 32 + quad * 8,
                  &KV[bb][par][fid][0][0]);
        }
        #pragma unroll
        for (int i = 0; i < 2; ++i) {
            const int fid = ws + i * 4;            // V frag: kh2*4 + nth
            const int kh2 = fid >> 2, nth = fid & 3;
            gld16(vbase + (long)(nth * 16 + l15) * SEQ + j0 + kh2 * 32 + quad * 8,
                  &KV[bb][par][8 + fid][0][0]);
        }
    };

    stage(par, 0);                         // chunks 0 and 1 (nch2 >= 17)
    __syncthreads();

    const int ns = (nch2 + 1) >> 1;        // super-steps (2 chunks each)
    #pragma unroll 1
    for (int t = 0; t < ns; ++t) {
        const int bb = t & 1;
        const int ch = 2 * t + par;
        if (ch + 2 < nch2) stage(ch + 2, bb ^ 1);

        if (ch < nch2) {
            const int j0 = ch * 64;
            short8 kf[2][2], vf[4];
            #pragma unroll
            for (int nt = 0; nt < 2; ++nt)
                #pragma unroll
                for (int ks = 0; ks < 2; ++ks)
                    kf[nt][ks] = *(const short8*)&KV[bb][par][(kh * 2 + nt) * 2 + ks][lane][0];
            #pragma unroll
            for (int nhh = 0; nhh < 4; ++nhh)
                vf[nhh] = *(const short8*)&KV[bb][par][8 + kh * 4 + nhh][lane][0];

            // ---------- tile 2 (always active) ----------
            {
                floatx4 sa[2];
                sa[0] = (floatx4){0.f, 0.f, 0.f, 0.f};
                sa[1] = (floatx4){0.f, 0.f, 0.f, 0.f};
                __builtin_amdgcn_s_setprio(1);
                #pragma unroll
                for (int nt = 0; nt < 2; ++nt) {
                    sa[nt] = __builtin_amdgcn_mfma_f32_16x16x32_bf16(q2f0, kf[nt][0], sa[nt], 0, 0, 0);
                    sa[nt] = __builtin_amdgcn_mfma_f32_16x16x32_bf16(q2f1, kf[nt][1], sa[nt], 0, 0, 0);
                }
                __builtin_amdgcn_s_setprio(0);
                #pragma unroll
                for (int r = 0; r < 4; ++r) {
                    const int sq = s2 + rg * 16 + quad * 4 + r;
                    #pragma unroll
                    for (int nt = 0; nt < 2; ++nt) {
                        const int sk = j0 + kh * 32 + nt * 16 + l15;
                        float pv = (sk > sq) ? 0.f : __expf(sa[nt][r] * 0.125f - 16.f);
                        sa[nt][r] = pv;
                        l2[r] += pv;
                    }
                }
                #pragma unroll
                for (int nt = 0; nt < 2; ++nt)
                    #pragma unroll
                    for (int r = 0; r < 4; ++r)
                        Plds[wv][quad * 4 + r][nt * 16 + l15] = f2bf(sa[nt][r]);
                short8 pf = *(const short8*)(&Plds[wv][l15][quad * 8]);
                __builtin_amdgcn_s_setprio(1);
                #pragma unroll
                for (int nhh = 0; nhh < 4; ++nhh)
                    o2[nhh] = __builtin_amdgcn_mfma_f32_16x16x32_bf16(pf, vf[nhh], o2[nhh], 0, 0, 0);
                __builtin_amdgcn_s_setprio(0);
            }

            // ---------- tile 1 (block-uniform gate) ----------
            if (ch < nch1) {
                floatx4 sa[2];
                sa[0] = (floatx4){0.f, 0.f, 0.f, 0.f};
                sa[1] = (floatx4){0.f, 0.f, 0.f, 0.f};
                __builtin_amdgcn_s_setprio(1);
                #pragma unroll
                for (int nt = 0; nt < 2; ++nt) {
                    sa[nt] = __builtin_amdgcn_mfma_f32_16x16x32_bf16(q1f0, kf[nt][0], sa[nt], 0, 0, 0);
                    sa[nt] = __builtin_amdgcn_mfma_f32_16x16x32_bf16(q1f1, kf[nt][1], sa[nt], 0, 0, 0);
                }
                __builtin_amdgcn_s_setprio(0);
                #pragma unroll
                for (int r = 0; r < 4; ++r) {
                    const int sq = s1 + rg * 16 + quad * 4 + r;
                    #pragma unroll
                    for (int nt = 0; nt < 2; ++nt) {
                        const int sk = j0 + kh * 32 + nt * 16 + l15;
                        float pv = (sk > sq) ? 0.f : __expf(sa[nt][r] * 0.125f - 16.f);
                        sa[nt][r] = pv;
                        l1[r] += pv;
                    }
                }
                #pragma unroll
                for (int nt = 0; nt < 2; ++nt)
                    #pragma unroll
                    for (int r = 0; r < 4; ++r)
                        Plds[wv][quad * 4 + r][nt * 16 + l15] = f2bf(sa[nt][r]);
                short8 pf = *(const short8*)(&Plds[wv][l15][quad * 8]);
                __builtin_amdgcn_s_setprio(1);
                #pragma unroll
                for (int nhh = 0; nhh < 4; ++nhh)
                    o1[nhh] = __builtin_amdgcn_mfma_f32_16x16x32_bf16(pf, vf[nhh], o1[nhh], 0, 0, 0);
                __builtin_amdgcn_s_setprio(0);
            }
        }
        __syncthreads();   // drains this wave's staging vmcnt; fences buffer swap
    }

    // reduce l across the 16 l15 lanes of each quad group
    #pragma unroll
    for (int msk = 1; msk <= 8; msk <<= 1) {
        #pragma unroll
        for (int r = 0; r < 4; ++r) {
            l1[r] += __shfl_xor(l1[r], msk, 64);
            l2[r] += __shfl_xor(l2[r], msk, 64);
        }
    }

    // 4-way (kh,par) merge: groups 1..3 write partials, group 0 sums+writes.
    const int g = (par << 1) | kh;
    if (g != 0) {
        const int slot = g - 1;
        #pragma unroll
        for (int nhh = 0; nhh < 4; ++nhh)
            #pragma unroll
            for (int r = 0; r < 4; ++r) {
                const int row = quad * 4 + r, col = nhh * 16 + l15;
                oM[(((0 * 3 + slot) * 2 + rg) * 16 + row) * 64 + col] = o1[nhh][r];
                oM[(((1 * 3 + slot) * 2 + rg) * 16 + row) * 64 + col] = o2[nhh][r];
            }
        if (l15 == 0) {
            #pragma unroll
            for (int r = 0; r < 4; ++r) {
                lM[((0 * 3 + slot) * 2 + rg) * 16 + quad * 4 + r] = l1[r];
                lM[((1 * 3 + slot) * 2 + rg) * 16 + quad * 4 + r] = l2[r];
            }
        }
    }
    __syncthreads();
    if (g == 0) {
        #pragma unroll
        for (int r = 0; r < 4; ++r) {
            const int row = quad * 4 + r;
            float ls1 = l1[r], ls2 = l2[r];
            #pragma unroll
            for (int slot = 0; slot < 3; ++slot) {
                ls1 += lM[((0 * 3 + slot) * 2 + rg) * 16 + row];
                ls2 += lM[((1 * 3 + slot) * 2 + rg) * 16 + row];
            }
            const float inv1 = 1.f / ls1;
            const float inv2 = 1.f / ls2;
            #pragma unroll
            for (int nhh = 0; nhh < 4; ++nhh) {
                const int col = nhh * 16 + l15;
                float a1 = o1[nhh][r], a2 = o2[nhh][r];
                #pragma unroll
                for (int slot = 0; slot < 3; ++slot) {
                    a1 += oM[(((0 * 3 + slot) * 2 + rg) * 16 + row) * 64 + col];
                    a2 += oM[(((1 * 3 + slot) * 2 + rg) * 16 + row) * 64 + col];
                }
                out[((long)b * SEQ + s1 + rg * 16 + row) * HEAD + col] = a1 * inv1;
                out[((long)b * SEQ + s2 + rg * 16 + row) * HEAD + col] = a2 * inv2;
            }
        }
    }
}

extern "C" void kernel_launch(void* const* d_in, const int* in_sizes, int n_in,
                              void* d_out, int out_size, void* d_ws, size_t ws_size,
                              hipStream_t stream) {
    const float* x  = (const float*)d_in[0];
    const float* Wk = (const float*)d_in[1];
    const float* Wq = (const float*)d_in[2];
    const float* Wv = (const float*)d_in[3];
    float* out = (float*)d_out;

    short* Wf = (short*)d_ws;                          // 384 KiB
    short* q  = Wf + 3 * HEAD * EMB;                   // 2 MiB each
    short* k  = q + (long)BATCH * SEQ * HEAD;
    short* vt = k + (long)BATCH * SEQ * HEAD;

    hipLaunchKernelGGL(wtrans_kernel, dim3(96), dim3(256), 0, stream, Wk, Wq, Wv, Wf);
    hipLaunchKernelGGL(qkv_kernel, dim3(BATCH * SEQ / 64), dim3(512), 0, stream, x, Wf, q, k, vt);
    hipLaunchKernelGGL(attn_kernel, dim3(BATCH * 32), dim3(512), 0, stream, q, k, vt, out);
}

// Round 5
// 140.102 us; speedup vs baseline: 1.0062x; 1.0062x over previous
//
#include <hip/hip_runtime.h>
#include <hip/hip_bf16.h>

typedef __attribute__((ext_vector_type(8))) short short8;
typedef __attribute__((ext_vector_type(4))) short short4v;
typedef __attribute__((ext_vector_type(4))) float floatx4;

#define SEQ   2048
#define EMB   1024
#define HEAD  64
#define BATCH 8

// bf16 via round-half-up (2 VALU ops; ties P=2^-16, stats == RNE)
__device__ __forceinline__ short f2bf(float f) {
    union { float f; unsigned u; } a; a.f = f;
    return (short)((a.u + 0x8000u) >> 16);
}

__device__ __forceinline__ short8 pk8(floatx4 a, floatx4 b) {
    short8 r;
    #pragma unroll
    for (int i = 0; i < 4; ++i) {
        union { float f; unsigned u; } x1, x2;
        x1.f = a[i]; x2.f = b[i];
        r[i]     = (short)((x1.u + 0x8000u) >> 16);
        r[4 + i] = (short)((x2.u + 0x8000u) >> 16);
    }
    return r;
}

// async global->LDS, 16B per lane; LDS dst = uniform base + lane*16
__device__ __forceinline__ void gld16(const void* g, void* l) {
    __builtin_amdgcn_global_load_lds(
        (const __attribute__((address_space(1))) unsigned int*)g,
        (__attribute__((address_space(3))) unsigned int*)l,
        16, 0, 0);
}

// Wf: MFMA-fragment-ordered weights, bf16.
// fragid f = (mat*4 + nt)*32 + kchunk, mat 0=Wq 1=Wk 2=Wv.
// Wf[f*512 + lane*8 + j] = W[k = kchunk*32 + (lane>>4)*8 + j][h = nt*16 + (lane&15)]
__global__ void wtrans_kernel(const float* __restrict__ Wk,
                              const float* __restrict__ Wq,
                              const float* __restrict__ Wv,
                              short* __restrict__ Wf) {
    int gid  = blockIdx.x * 256 + threadIdx.x;   // 24576 total
    int lane = gid & 63;
    int fid  = gid >> 6;
    int chunk = fid & 31;
    int mnt  = fid >> 5;
    int mat  = mnt >> 2, nt = mnt & 3;
    const float* src = (mat == 0) ? Wq : (mat == 1) ? Wk : Wv;
    int n = lane & 15, quad = lane >> 4;
    int h = nt * 16 + n;
    short8 o8;
    #pragma unroll
    for (int j = 0; j < 8; ++j)
        o8[j] = f2bf(src[(chunk * 32 + quad * 8 + j) * 64 + h]);
    *(short8*)(Wf + (long)gid * 8) = o8;
}

// QKV v4 (unchanged from round 4): block = 64 rows, 512 threads, 8 waves =
// (rg = 16-row group, 0..3) x (nh = 96-col half) -> 2 waves/SIMD. Pure
// M-split, no merge. x register double-buffer in paired even/odd loop.
__global__ __launch_bounds__(512, 1) void qkv_kernel(const float* __restrict__ x,
                                                     const short* __restrict__ Wf,
                                                     short* __restrict__ q,
                                                     short* __restrict__ k,
                                                     short* __restrict__ vt) {
    __shared__ short LW[2][12][4][64][8];   // 96 KB: [buf][mnt][kchunk][lane][8]
    const int wv   = threadIdx.x >> 6;      // 0..7
    const int lane = threadIdx.x & 63;
    const int l15  = lane & 15;
    const int quad = lane >> 4;
    const int rg   = wv >> 1;              // row group (16 rows), 0..3
    const int nh   = wv & 1;               // N half (6 ntiles)
    const int row0 = blockIdx.x * 64;

    floatx4 acc[6];
    #pragma unroll
    for (int f = 0; f < 6; ++f) acc[f] = (floatx4){0.f, 0.f, 0.f, 0.f};

    const float* xr0 = x + (long)(row0 + rg * 16 + l15) * EMB + quad * 8;

    floatx4 xva[8], xvb[8];

    auto stageW = [&](int gnext, int dst) {
        #pragma unroll
        for (int i = 0; i < 6; ++i) {
            const int s = wv * 6 + i, mnt = s >> 2, c = s & 3;
            gld16(Wf + (long)(mnt * 32 + gnext * 4 + c) * 512 + lane * 8,
                  &LW[dst][mnt][c][0][0]);
        }
    };
    auto loadx = [&](floatx4 (&xv)[8], int g) {
        #pragma unroll
        for (int c = 0; c < 4; ++c) {
            const float* p0 = xr0 + g * 128 + c * 32;
            xv[2 * c + 0] = *(const floatx4*)(p0);
            xv[2 * c + 1] = *(const floatx4*)(p0 + 4);
        }
    };
    auto compute = [&](int bb, floatx4 (&xc)[8]) {
        #pragma unroll
        for (int c = 0; c < 4; ++c) {
            short8 a0 = pk8(xc[2 * c + 0], xc[2 * c + 1]);
            #pragma unroll
            for (int i = 0; i < 6; ++i) {
                short8 bf = *(const short8*)&LW[bb][nh * 6 + i][c][lane][0];
                acc[i] = __builtin_amdgcn_mfma_f32_16x16x32_bf16(a0, bf, acc[i], 0, 0, 0);
            }
        }
    };

    stageW(0, 0);
    loadx(xva, 0);
    __syncthreads();

    #pragma unroll 1
    for (int t = 0; t < 4; ++t) {
        const int g0 = 2 * t;
        // even group g0: consume xva + LW[0]; prefetch g0+1 -> LW[1], xvb
        stageW(g0 + 1, 1);
        loadx(xvb, g0 + 1);
        compute(0, xva);
        __syncthreads();
        // odd group g0+1: consume xvb + LW[1]; prefetch g0+2 -> LW[0], xva
        if (t < 3) {
            stageW(g0 + 2, 0);
            loadx(xva, g0 + 2);
        }
        compute(1, xvb);
        __syncthreads();
    }

    // epilogue: wave owns rows rg*16..+15, ntiles nh*6..+5
    const int bidx = row0 >> 11;
    #pragma unroll
    for (int i = 0; i < 6; ++i) {
        const int mnt = nh * 6 + i;
        const int mat = mnt >> 2, ntl = mnt & 3;
        const int col = ntl * 16 + l15;
        const floatx4 av = acc[i];
        const long rbase = row0 + rg * 16 + quad * 4;
        if (mat == 0) {
            #pragma unroll
            for (int r = 0; r < 4; ++r)
                q[(rbase + r) * HEAD + col] = f2bf(av[r]);
        } else if (mat == 1) {
            #pragma unroll
            for (int r = 0; r < 4; ++r)
                k[(rbase + r) * HEAD + col] = f2bf(av[r]);
        } else {
            short4v vv;
            #pragma unroll
            for (int r = 0; r < 4; ++r) vv[r] = f2bf(av[r]);
            const int srow = (int)(rbase & (SEQ - 1));
            *(short4v*)(vt + ((long)bidx * HEAD + col) * SEQ + srow) = vv;
        }
    }
}

// Attention v3 (tile-interleave, isolated test): block = tile pair (p, 63-p)
// of 32 q-rows each. 8 waves = (par = chunk parity) x (kh) x (rg); 2
// waves/SIMD, one barrier per two chunks. Tiles 1 and 2 INTERLEAVED within
// a chunk (QK both -> exp both -> P-write both -> P-read both -> PV both):
// the LDS P-transpose turnaround is paid once per chunk instead of twice.
// Fixed-base softmax exp(s/8-16) => (kh,par) partials merge by plain sum.
__global__ __launch_bounds__(512, 2) void attn_kernel(const short* __restrict__ q,
                                                      const short* __restrict__ k,
                                                      const short* __restrict__ vt,
                                                      float* __restrict__ out) {
    // LDS arena: main loop KV 64 KB + Plds 20 KB (2 x 8 wave slots);
    // epilogue overlays oM 48 KB + lM 768 B on the dead KV region.
    __shared__ __align__(16) char smem[86016];
    auto KV   = (short (*)[2][16][64][8])smem;        // [bb][par][fid][lane][j]
    auto Plds = (short (*)[16][40])(smem + 65536);    // [slot16][row][col]
    float* oM = (float*)smem;                         // [tile2][slot3][rg2][row16][col64]
    float* lM = (float*)(smem + 49152);               // [tile2][slot3][rg2][row16]

    const int wv   = (int)threadIdx.x >> 6;
    const int lane = (int)threadIdx.x & 63;
    const int l15  = lane & 15;
    const int quad = lane >> 4;
    const int ws   = wv & 3;               // sub-id within parity group
    const int rg   = ws & 1;               // row-group within 32-row tile
    const int kh   = ws >> 1;              // key-half within BK=64 chunk
    const int par  = wv >> 2;              // chunk parity
    const int b    = blockIdx.x & 7;
    const int p    = blockIdx.x >> 3;      // 0..31
    const int t2   = 63 - p;
    const int s1   = p * 32, s2 = t2 * 32;
    const int nch1 = (p >> 1) + 1;         // 1..16
    const int nch2 = (t2 >> 1) + 1;        // 17..32; nch1+nch2 == 33

    const short* kbase = k  + (long)b * SEQ * HEAD;
    const short* vbase = vt + (long)b * HEAD * SEQ;

    const short* q1p = q + ((long)b * SEQ + s1 + rg * 16 + l15) * HEAD + quad * 8;
    const short* q2p = q + ((long)b * SEQ + s2 + rg * 16 + l15) * HEAD + quad * 8;
    short8 q1f0 = *(const short8*)(q1p), q1f1 = *(const short8*)(q1p + 32);
    short8 q2f0 = *(const short8*)(q2p), q2f1 = *(const short8*)(q2p + 32);

    floatx4 o1[4], o2[4];
    #pragma unroll
    for (int nhh = 0; nhh < 4; ++nhh) {
        o1[nhh] = (floatx4){0.f, 0.f, 0.f, 0.f};
        o2[nhh] = (floatx4){0.f, 0.f, 0.f, 0.f};
    }
    float l1[4] = {0.f, 0.f, 0.f, 0.f};
    float l2[4] = {0.f, 0.f, 0.f, 0.f};

    // stage one chunk of this wave's parity into KV[bb][par]; 4 waves/parity
    // cover 16 frags (fid 0-7 K, 8-15 V) at 4 gld16 per wave.
    auto stage = [&](int ch, int bb) {
        const int j0 = ch * 64;
        #pragma unroll
        for (int i = 0; i < 2; ++i) {
            const int fid = ws + i * 4;            // K frag: (ntg<<1)|ks
            const int ntg = fid >> 1, ks = fid & 1;
            gld16(kbase + (long)(j0 + ntg * 16 + l15) * HEAD + ks * 32 + quad * 8,
                  &KV[bb][par][fid][0][0]);
        }
        #pragma unroll
        for (int i = 0; i < 2; ++i) {
            const int fid = ws + i * 4;            // V frag: kh2*4 + nth
            const int kh2 = fid >> 2, nth = fid & 3;
            gld16(vbase + (long)(nth * 16 + l15) * SEQ + j0 + kh2 * 32 + quad * 8,
                  &KV[bb][par][8 + fid][0][0]);
        }
    };

    stage(par, 0);                         // chunks 0 and 1 (nch2 >= 17)
    __syncthreads();

    const int ns = (nch2 + 1) >> 1;        // super-steps (2 chunks each)
    #pragma unroll 1
    for (int t = 0; t < ns; ++t) {
        const int bb = t & 1;
        const int ch = 2 * t + par;
        if (ch + 2 < nch2) stage(ch + 2, bb ^ 1);

        if (ch < nch2) {
            const int j0 = ch * 64;
            const bool act1 = (ch < nch1);         // wave-uniform
            short8 kf[2][2], vf[4];
            #pragma unroll
            for (int nt = 0; nt < 2; ++nt)
                #pragma unroll
                for (int ks = 0; ks < 2; ++ks)
                    kf[nt][ks] = *(const short8*)&KV[bb][par][(kh * 2 + nt) * 2 + ks][lane][0];
            #pragma unroll
            for (int nhh = 0; nhh < 4; ++nhh)
                vf[nhh] = *(const short8*)&KV[bb][par][8 + kh * 4 + nhh][lane][0];

            // ---- QK^T, both tiles ----
            floatx4 sa2[2], sa1[2];
            sa2[0] = (floatx4){0.f, 0.f, 0.f, 0.f};
            sa2[1] = (floatx4){0.f, 0.f, 0.f, 0.f};
            sa1[0] = (floatx4){0.f, 0.f, 0.f, 0.f};
            sa1[1] = (floatx4){0.f, 0.f, 0.f, 0.f};
            __builtin_amdgcn_s_setprio(1);
            #pragma unroll
            for (int nt = 0; nt < 2; ++nt) {
                sa2[nt] = __builtin_amdgcn_mfma_f32_16x16x32_bf16(q2f0, kf[nt][0], sa2[nt], 0, 0, 0);
                sa2[nt] = __builtin_amdgcn_mfma_f32_16x16x32_bf16(q2f1, kf[nt][1], sa2[nt], 0, 0, 0);
            }
            if (act1) {
                #pragma unroll
                for (int nt = 0; nt < 2; ++nt) {
                    sa1[nt] = __builtin_amdgcn_mfma_f32_16x16x32_bf16(q1f0, kf[nt][0], sa1[nt], 0, 0, 0);
                    sa1[nt] = __builtin_amdgcn_mfma_f32_16x16x32_bf16(q1f1, kf[nt][1], sa1[nt], 0, 0, 0);
                }
            }
            __builtin_amdgcn_s_setprio(0);

            // ---- softmax (fixed base), both tiles ----
            #pragma unroll
            for (int r = 0; r < 4; ++r) {
                const int sq2 = s2 + rg * 16 + quad * 4 + r;
                #pragma unroll
                for (int nt = 0; nt < 2; ++nt) {
                    const int sk = j0 + kh * 32 + nt * 16 + l15;
                    float pv = (sk > sq2) ? 0.f : __expf(sa2[nt][r] * 0.125f - 16.f);
                    sa2[nt][r] = pv;
                    l2[r] += pv;
                }
            }
            if (act1) {
                #pragma unroll
                for (int r = 0; r < 4; ++r) {
                    const int sq1 = s1 + rg * 16 + quad * 4 + r;
                    #pragma unroll
                    for (int nt = 0; nt < 2; ++nt) {
                        const int sk = j0 + kh * 32 + nt * 16 + l15;
                        float pv = (sk > sq1) ? 0.f : __expf(sa1[nt][r] * 0.125f - 16.f);
                        sa1[nt][r] = pv;
                        l1[r] += pv;
                    }
                }
            }

            // ---- P transpose through LDS, both tiles (one turnaround) ----
            #pragma unroll
            for (int nt = 0; nt < 2; ++nt)
                #pragma unroll
                for (int r = 0; r < 4; ++r)
                    Plds[wv][quad * 4 + r][nt * 16 + l15] = f2bf(sa2[nt][r]);
            if (act1) {
                #pragma unroll
                for (int nt = 0; nt < 2; ++nt)
                    #pragma unroll
                    for (int r = 0; r < 4; ++r)
                        Plds[8 + wv][quad * 4 + r][nt * 16 + l15] = f2bf(sa1[nt][r]);
            }
            short8 pf2 = *(const short8*)(&Plds[wv][l15][quad * 8]);
            __builtin_amdgcn_s_setprio(1);
            #pragma unroll
            for (int nhh = 0; nhh < 4; ++nhh)
                o2[nhh] = __builtin_amdgcn_mfma_f32_16x16x32_bf16(pf2, vf[nhh], o2[nhh], 0, 0, 0);
            if (act1) {
                short8 pf1 = *(const short8*)(&Plds[8 + wv][l15][quad * 8]);
                #pragma unroll
                for (int nhh = 0; nhh < 4; ++nhh)
                    o1[nhh] = __builtin_amdgcn_mfma_f32_16x16x32_bf16(pf1, vf[nhh], o1[nhh], 0, 0, 0);
            }
            __builtin_amdgcn_s_setprio(0);
        }
        __syncthreads();   // drains this wave's staging vmcnt; fences buffer swap
    }

    // reduce l across the 16 l15 lanes of each quad group
    #pragma unroll
    for (int msk = 1; msk <= 8; msk <<= 1) {
        #pragma unroll
        for (int r = 0; r < 4; ++r) {
            l1[r] += __shfl_xor(l1[r], msk, 64);
            l2[r] += __shfl_xor(l2[r], msk, 64);
        }
    }

    // 4-way (kh,par) merge: groups 1..3 write partials, group 0 sums+writes.
    const int g = (par << 1) | kh;
    if (g != 0) {
        const int slot = g - 1;
        #pragma unroll
        for (int nhh = 0; nhh < 4; ++nhh)
            #pragma unroll
            for (int r = 0; r < 4; ++r) {
                const int row = quad * 4 + r, col = nhh * 16 + l15;
                oM[(((0 * 3 + slot) * 2 + rg) * 16 + row) * 64 + col] = o1[nhh][r];
                oM[(((1 * 3 + slot) * 2 + rg) * 16 + row) * 64 + col] = o2[nhh][r];
            }
        if (l15 == 0) {
            #pragma unroll
            for (int r = 0; r < 4; ++r) {
                lM[((0 * 3 + slot) * 2 + rg) * 16 + quad * 4 + r] = l1[r];
                lM[((1 * 3 + slot) * 2 + rg) * 16 + quad * 4 + r] = l2[r];
            }
        }
    }
    __syncthreads();
    if (g == 0) {
        #pragma unroll
        for (int r = 0; r < 4; ++r) {
            const int row = quad * 4 + r;
            float ls1 = l1[r], ls2 = l2[r];
            #pragma unroll
            for (int slot = 0; slot < 3; ++slot) {
                ls1 += lM[((0 * 3 + slot) * 2 + rg) * 16 + row];
                ls2 += lM[((1 * 3 + slot) * 2 + rg) * 16 + row];
            }
            const float inv1 = 1.f / ls1;
            const float inv2 = 1.f / ls2;
            #pragma unroll
            for (int nhh = 0; nhh < 4; ++nhh) {
                const int col = nhh * 16 + l15;
                float a1 = o1[nhh][r], a2 = o2[nhh][r];
                #pragma unroll
                for (int slot = 0; slot < 3; ++slot) {
                    a1 += oM[(((0 * 3 + slot) * 2 + rg) * 16 + row) * 64 + col];
                    a2 += oM[(((1 * 3 + slot) * 2 + rg) * 16 + row) * 64 + col];
                }
                out[((long)b * SEQ + s1 + rg * 16 + row) * HEAD + col] = a1 * inv1;
                out[((long)b * SEQ + s2 + rg * 16 + row) * HEAD + col] = a2 * inv2;
            }
        }
    }
}

extern "C" void kernel_launch(void* const* d_in, const int* in_sizes, int n_in,
                              void* d_out, int out_size, void* d_ws, size_t ws_size,
                              hipStream_t stream) {
    const float* x  = (const float*)d_in[0];
    const float* Wk = (const float*)d_in[1];
    const float* Wq = (const float*)d_in[2];
    const float* Wv = (const float*)d_in[3];
    float* out = (float*)d_out;

    short* Wf = (short*)d_ws;                          // 384 KiB
    short* q  = Wf + 3 * HEAD * EMB;                   // 2 MiB each
    short* k  = q + (long)BATCH * SEQ * HEAD;
    short* vt = k + (long)BATCH * SEQ * HEAD;

    hipLaunchKernelGGL(wtrans_kernel, dim3(96), dim3(256), 0, stream, Wk, Wq, Wv, Wf);
    hipLaunchKernelGGL(qkv_kernel, dim3(BATCH * SEQ / 64), dim3(512), 0, stream, x, Wf, q, k, vt);
    hipLaunchKernelGGL(attn_kernel, dim3(BATCH * 32), dim3(512), 0, stream, q, k, vt, out);
}